// Round 6
// baseline (258.302 us; speedup 1.0000x reference)
//
#include <hip/hip_runtime.h>

#define Hh 160
#define Ww 160
#define HW 25600
#define Bb 8
#define Cc 64
#define Oo 64
#define NPIX (Bb * HW)   // 204800
#define WROW 72          // shorts per padded LDS weight row (144 B)
#define BPX 128          // pixels per dcn block
#define NBLK (NPIX / BPX) // 1600

typedef __bf16 bf16x8 __attribute__((ext_vector_type(8)));
typedef float  f32x4  __attribute__((ext_vector_type(4)));
typedef float  f32x2  __attribute__((ext_vector_type(2)));

__device__ inline unsigned rnd_bf(float a) {
    unsigned u = __float_as_uint(a);
    return (u + 0x7FFFu + ((u >> 16) & 1u)) >> 16;   // RNE (prep only)
}
// fast round-half-up pack of two f32 -> packed bf16x2
__device__ inline unsigned pack_bf2(float a, float b) {
    unsigned ua = __float_as_uint(a) + 0x8000u;
    unsigned ub = __float_as_uint(b) + 0x8000u;
    return __builtin_amdgcn_perm(ub, ua, 0x07060302);
}
__device__ inline f32x2 up2(unsigned u) {
    f32x2 r;
    r.x = __uint_as_float(u << 16);
    r.y = __uint_as_float(u & 0xffff0000u);
    return r;
}
__device__ inline unsigned blend4(unsigned u00, unsigned u01, unsigned u10, unsigned u11,
                                  float w00, float w01, float w10, float w11) {
    f32x2 r = up2(u00) * w00 + up2(u01) * w01 + up2(u10) * w10 + up2(u11) * w11;
    return pack_bf2(r.x, r.y);
}
union UV { uint4 u; bf16x8 v; };
__device__ inline bf16x8 as_bf(uint4 u) { UV c; c.u = u; return c.v; }

// ---- init: [blocks 0..3199] NCHW->NHWC bf16 transpose; [3200..] weight prep ---
__global__ __launch_bounds__(256) void init_kernel(
    const float* __restrict__ x, unsigned short* __restrict__ xhwc,
    const float* __restrict__ w_dcn, const float* __restrict__ b_dcn,
    const float* __restrict__ w_off,
    const float* __restrict__ gamma, const float* __restrict__ beta,
    const float* __restrict__ run_mean, const float* __restrict__ run_var,
    unsigned short* __restrict__ wtb, unsigned short* __restrict__ woffb,
    float* __restrict__ scaleb)
{
    __shared__ float tile[64 * 65];
    int t = threadIdx.x;
    if (blockIdx.x < 3200) {
        int blk = blockIdx.x;
        int b = blk / 400, hw0 = (blk % 400) * 64;
        int lane = t & 63, grp = t >> 6;
        const float* xp = x + (size_t)b * Cc * HW + hw0 + lane;
#pragma unroll
        for (int i = 0; i < 16; ++i) {
            int c = i * 4 + grp;
            tile[lane * 65 + c] = xp[(size_t)c * HW];
        }
        __syncthreads();
        int px  = t >> 2;
        int ch0 = (t & 3) * 16;
        const float* row = tile + px * 65 + ch0;
        unsigned u[8];
#pragma unroll
        for (int j = 0; j < 8; ++j) u[j] = pack_bf2(row[2 * j], row[2 * j + 1]);
        unsigned short* dst = xhwc + ((size_t)(b * HW + hw0 + px)) * 64 + ch0;
        *(uint4*)dst       = make_uint4(u[0], u[1], u[2], u[3]);
        *(uint4*)(dst + 8) = make_uint4(u[4], u[5], u[6], u[7]);
    } else {
        int i = (blockIdx.x - 3200) * 256 + t;
        if (i < 9 * Oo * Cc) {                 // wtb: [k][o][c]
            int k = i >> 12, rem = i & 4095;
            int o = rem >> 6, c = rem & 63;
            wtb[i] = (unsigned short)rnd_bf(w_dcn[(o * Cc + c) * 9 + k]);
        }
        if (i < 9 * 32 * Cc) {                 // woffb: [k][o pad32][c]
            int k = i >> 11, rem = i & 2047;
            int o = rem >> 6, c = rem & 63;
            float v = (o < 18) ? w_off[(o * Cc + c) * 9 + k] : 0.0f;
            woffb[i] = (unsigned short)rnd_bf(v);
        }
        if (i < Oo) {
            float inv = gamma[i] * rsqrtf(run_var[i] + 1e-5f);
            scaleb[i]      = inv;
            scaleb[Oo + i] = b_dcn[i] * inv + (beta[i] - run_mean[i] * inv);
        }
    }
}

// bilinear sample 16 channels (this lane's quad chunk) of one pixel -> A0,A1
__device__ inline void sample_one(
    const unsigned short* __restrict__ xq, float py, float px,
    bf16x8& A0, bf16x8& A1)
{
    float y0f = floorf(py), x0f = floorf(px);
    float fy = py - y0f, fx = px - x0f;
    int y0 = (int)y0f, x0i = (int)x0f;
    int y1 = y0 + 1, x1 = x0i + 1;
    bool vy0 = (y0 >= 0) & (y0 < Hh), vy1 = (y1 >= 0) & (y1 < Hh);
    bool vx0 = (x0i >= 0) & (x0i < Ww), vx1 = (x1 >= 0) & (x1 < Ww);
    float w00 = (vy0 & vx0) ? (1.0f - fy) * (1.0f - fx) : 0.0f;
    float w01 = (vy0 & vx1) ? (1.0f - fy) * fx : 0.0f;
    float w10 = (vy1 & vx0) ? fy * (1.0f - fx) : 0.0f;
    float w11 = (vy1 & vx1) ? fy * fx : 0.0f;
    int cy0 = min(max(y0, 0), Hh - 1), cy1 = min(max(y1, 0), Hh - 1);
    int cx0 = min(max(x0i, 0), Ww - 1), cx1 = min(max(x1, 0), Ww - 1);

    const unsigned short* s00 = xq + (size_t)(cy0 * Ww + cx0) * 64;
    const unsigned short* s01 = xq + (size_t)(cy0 * Ww + cx1) * 64;
    const unsigned short* s10 = xq + (size_t)(cy1 * Ww + cx0) * 64;
    const unsigned short* s11 = xq + (size_t)(cy1 * Ww + cx1) * 64;
    uint4 a00 = *(const uint4*)(s00), b00 = *(const uint4*)(s00 + 32);
    uint4 a01 = *(const uint4*)(s01), b01 = *(const uint4*)(s01 + 32);
    uint4 a10 = *(const uint4*)(s10), b10 = *(const uint4*)(s10 + 32);
    uint4 a11 = *(const uint4*)(s11), b11 = *(const uint4*)(s11 + 32);

    uint4 o0, o1;
    o0.x = blend4(a00.x, a01.x, a10.x, a11.x, w00, w01, w10, w11);
    o0.y = blend4(a00.y, a01.y, a10.y, a11.y, w00, w01, w10, w11);
    o0.z = blend4(a00.z, a01.z, a10.z, a11.z, w00, w01, w10, w11);
    o0.w = blend4(a00.w, a01.w, a10.w, a11.w, w00, w01, w10, w11);
    o1.x = blend4(b00.x, b01.x, b10.x, b11.x, w00, w01, w10, w11);
    o1.y = blend4(b00.y, b01.y, b10.y, b11.y, w00, w01, w10, w11);
    o1.z = blend4(b00.z, b01.z, b10.z, b11.z, w00, w01, w10, w11);
    o1.w = blend4(b00.w, b01.w, b10.w, b11.w, w00, w01, w10, w11);
    A0 = as_bf(o0);
    A1 = as_bf(o1);
}

// one projection tap: sample both pixel tiles, 8 LDS B-reads, 16 MFMAs
__device__ inline void tap_compute(
    int tap, const short* __restrict__ wq, int m,
    int h0, int w0, int h1, int w1, int px0, int px1,
    const unsigned short* __restrict__ xq, const float* __restrict__ offb,
    f32x4& c00, f32x4& c01, f32x4& c02, f32x4& c03,
    f32x4& c10, f32x4& c11, f32x4& c12, f32x4& c13)
{
    int ky = tap / 3 - 1, kx = tap % 3 - 1;
    float oy0 = offb[px0 * 19 + 2 * tap], ox0 = offb[px0 * 19 + 2 * tap + 1];
    float oy1 = offb[px1 * 19 + 2 * tap], ox1 = offb[px1 * 19 + 2 * tap + 1];
    bf16x8 A00, A01, A10, A11;
    sample_one(xq, (float)(h0 + ky) + oy0, (float)(w0 + kx) + ox0, A00, A01);
    sample_one(xq, (float)(h1 + ky) + oy1, (float)(w1 + kx) + ox1, A10, A11);

    bf16x8 B0, B1;
#define NSTEP(nt, d0, d1)                                            \
    B0 = *(const bf16x8*)(wq + (m + 16 * nt) * WROW);                \
    B1 = *(const bf16x8*)(wq + (m + 16 * nt) * WROW + 32);           \
    d0 = __builtin_amdgcn_mfma_f32_16x16x32_bf16(A00, B0, d0, 0, 0, 0); \
    d0 = __builtin_amdgcn_mfma_f32_16x16x32_bf16(A01, B1, d0, 0, 0, 0); \
    d1 = __builtin_amdgcn_mfma_f32_16x16x32_bf16(A10, B0, d1, 0, 0, 0); \
    d1 = __builtin_amdgcn_mfma_f32_16x16x32_bf16(A11, B1, d1, 0, 0, 0);
    NSTEP(0, c00, c10)
    NSTEP(1, c01, c11)
    NSTEP(2, c02, c12)
    NSTEP(3, c03, c13)
#undef NSTEP
}

// ---- fused: offset-conv(MFMA) + deform-sample + projection(MFMA) + BN + ReLU --
// 256 thr = 4 waves; 128 px/block, 32 px/wave (2 M-tiles). Weights pair-staged.
__global__ __launch_bounds__(256, 3) void dcn_kernel(
    const unsigned short* __restrict__ xhwc,
    const unsigned short* __restrict__ wtb,     // [9][64][64]
    const unsigned short* __restrict__ woffb,   // [9][32][64]
    const float* __restrict__ b_off,
    const float* __restrict__ scaleb,
    float* __restrict__ out)
{
    __shared__ __align__(16) short arena[4 * 64 * WROW];  // 36864 B
    __shared__ float offb[BPX * 19];                      //  9728 B

    const int t = threadIdx.x;
    const int lane = t & 63, wv = t >> 6;
    const int m = lane & 15, quad = lane >> 4;

    int blk = blockIdx.x;
    int nb  = (blk & 7) * (NBLK / 8) + (blk >> 3);  // XCD slab: 1 image/XCD
    int b   = nb / (NBLK / 8);
    int hw0 = (nb % (NBLK / 8)) * BPX;
    int px0 = wv * 32 + m, px1 = px0 + 16;
    int hwa = hw0 + px0, hwb = hw0 + px1;
    int h0 = hwa / Ww, w0 = hwa % Ww;
    int h1 = hwb / Ww, w1 = hwb % Ww;

    const size_t bbase = (size_t)b * HW;
    const unsigned short* xq = xhwc + bbase * 64 + quad * 8;
    const uint4* wtb4  = (const uint4*)wtb;
    const uint4* wofb4 = (const uint4*)woffb;

    // ================= phase 1: offset conv (dbuf LDS weights) ================
    f32x4 oa00 = {0,0,0,0}, oa01 = {0,0,0,0}, oa10 = {0,0,0,0}, oa11 = {0,0,0,0};
    {   // stage tap 0 -> buf 0
        uint4 v = wofb4[t];
        *(uint4*)((char*)arena + (t >> 3) * 144 + (t & 7) * 16) = v;
    }
    __syncthreads();
#pragma unroll 1
    for (int k = 0; k < 9; ++k) {
        int cur = k & 1;
        if (k < 8) {
            uint4 v = wofb4[(k + 1) * 256 + t];
            *(uint4*)((char*)arena + (cur ^ 1) * 4608 + (t >> 3) * 144 + (t & 7) * 16) = v;
        }
        int ky = k / 3 - 1, kx = k % 3 - 1;
        int hp0 = h0 + ky, wp0 = w0 + kx;
        int hp1 = h1 + ky, wp1 = w1 + kx;
        bool ok0 = (hp0 >= 0) & (hp0 < Hh) & (wp0 >= 0) & (wp0 < Ww);
        bool ok1 = (hp1 >= 0) & (hp1 < Hh) & (wp1 >= 0) & (wp1 < Ww);
        const unsigned short* s0 =
            xq + (size_t)(min(max(hp0, 0), Hh - 1) * Ww + min(max(wp0, 0), Ww - 1)) * 64;
        const unsigned short* s1 =
            xq + (size_t)(min(max(hp1, 0), Hh - 1) * Ww + min(max(wp1, 0), Ww - 1)) * 64;
        uint4 r0 = *(const uint4*)(s0), r1 = *(const uint4*)(s0 + 32);
        uint4 r2 = *(const uint4*)(s1), r3 = *(const uint4*)(s1 + 32);
        if (!ok0) { r0 = make_uint4(0,0,0,0); r1 = make_uint4(0,0,0,0); }
        if (!ok1) { r2 = make_uint4(0,0,0,0); r3 = make_uint4(0,0,0,0); }
        bf16x8 A00 = as_bf(r0), A01 = as_bf(r1), A10 = as_bf(r2), A11 = as_bf(r3);

        const short* wb = arena + cur * 2304 + quad * 8;
        bf16x8 B0 = *(const bf16x8*)(wb + m * WROW);
        bf16x8 B1 = *(const bf16x8*)(wb + m * WROW + 32);
        oa00 = __builtin_amdgcn_mfma_f32_16x16x32_bf16(A00, B0, oa00, 0, 0, 0);
        oa00 = __builtin_amdgcn_mfma_f32_16x16x32_bf16(A01, B1, oa00, 0, 0, 0);
        oa10 = __builtin_amdgcn_mfma_f32_16x16x32_bf16(A10, B0, oa10, 0, 0, 0);
        oa10 = __builtin_amdgcn_mfma_f32_16x16x32_bf16(A11, B1, oa10, 0, 0, 0);
        B0 = *(const bf16x8*)(wb + (m + 16) * WROW);
        B1 = *(const bf16x8*)(wb + (m + 16) * WROW + 32);
        oa01 = __builtin_amdgcn_mfma_f32_16x16x32_bf16(A00, B0, oa01, 0, 0, 0);
        oa01 = __builtin_amdgcn_mfma_f32_16x16x32_bf16(A01, B1, oa01, 0, 0, 0);
        oa11 = __builtin_amdgcn_mfma_f32_16x16x32_bf16(A10, B0, oa11, 0, 0, 0);
        oa11 = __builtin_amdgcn_mfma_f32_16x16x32_bf16(A11, B1, oa11, 0, 0, 0);
        __syncthreads();
    }

    // offsets -> LDS; stage projection pair {0,1} -> buf 0
    {
        float bo0 = b_off[m];
        float bo1 = (m < 2) ? b_off[16 + m] : 0.0f;
#pragma unroll
        for (int r = 0; r < 4; ++r) {
            int pp0 = wv * 32 + quad * 4 + r;
            int pp1 = pp0 + 16;
            offb[pp0 * 19 + m] = oa00[r] + bo0;
            offb[pp1 * 19 + m] = oa10[r] + bo0;
            if (m < 2) {
                offb[pp0 * 19 + 16 + m] = oa01[r] + bo1;
                offb[pp1 * 19 + 16 + m] = oa11[r] + bo1;
            }
        }
    }
#pragma unroll
    for (int q = t; q < 1024; q += 256) {
        uint4 v = wtb4[q];
        *(uint4*)((char*)arena + (q >> 3) * 144 + (q & 7) * 16) = v;
    }
    __syncthreads();

    // ================= phase 2: deform sample + projection =================
    f32x4 c00 = {0,0,0,0}, c01 = {0,0,0,0}, c02 = {0,0,0,0}, c03 = {0,0,0,0};
    f32x4 c10 = {0,0,0,0}, c11 = {0,0,0,0}, c12 = {0,0,0,0}, c13 = {0,0,0,0};
#pragma unroll 1
    for (int ps = 0; ps < 4; ++ps) {
        int buf = ps & 1;
        {   // stage next: pairs 1..3 are 1024 chunks; "pair 4" is tap 8 only
            const uint4* g = wtb4 + (2 * (ps + 1)) * 512;
            int n = (ps == 3) ? 512 : 1024;
            char* base = (char*)arena + (buf ^ 1) * 18432;
#pragma unroll
            for (int q = t; q < n; q += 256) {
                uint4 v = g[q];
                *(uint4*)(base + (q >> 3) * 144 + (q & 7) * 16) = v;
            }
        }
        const short* wq0 = (const short*)((const char*)arena + buf * 18432) + quad * 8;
        tap_compute(2 * ps, wq0, m, h0, w0, h1, w1, px0, px1, xq, offb,
                    c00, c01, c02, c03, c10, c11, c12, c13);
        tap_compute(2 * ps + 1, wq0 + 4608, m, h0, w0, h1, w1, px0, px1, xq, offb,
                    c00, c01, c02, c03, c10, c11, c12, c13);
        __syncthreads();
    }
    {   // tap 8 from buf 0 (staged during ps=3)
        const short* wq0 = (const short*)((const char*)arena) + quad * 8;
        tap_compute(8, wq0, m, h0, w0, h1, w1, px0, px1, xq, offb,
                    c00, c01, c02, c03, c10, c11, c12, c13);
    }

    // ---- epilogue: direct float4 stores, fused BN + ReLU ----
#pragma unroll
    for (int mt = 0; mt < 2; ++mt) {
#pragma unroll
        for (int nt = 0; nt < 4; ++nt) {
            f32x4 a;
            if (mt == 0) a = (nt == 0) ? c00 : (nt == 1) ? c01 : (nt == 2) ? c02 : c03;
            else         a = (nt == 0) ? c10 : (nt == 1) ? c11 : (nt == 2) ? c12 : c13;
            int o = nt * 16 + m;
            float sc = scaleb[o];
            float bs = scaleb[Oo + o];
            float4 r;
            r.x = fmaxf(a[0] * sc + bs, 0.0f);
            r.y = fmaxf(a[1] * sc + bs, 0.0f);
            r.z = fmaxf(a[2] * sc + bs, 0.0f);
            r.w = fmaxf(a[3] * sc + bs, 0.0f);
            float* op = out + ((size_t)b * Oo + o) * HW + hw0 + wv * 32 + mt * 16 + quad * 4;
            *(float4*)op = r;
        }
    }
}

extern "C" void kernel_launch(void* const* d_in, const int* in_sizes, int n_in,
                              void* d_out, int out_size, void* d_ws, size_t ws_size,
                              hipStream_t stream) {
    const float* x        = (const float*)d_in[0];
    const float* w_off    = (const float*)d_in[1];
    const float* b_off    = (const float*)d_in[2];
    const float* w_dcn    = (const float*)d_in[3];
    const float* b_dcn    = (const float*)d_in[4];
    const float* gamma    = (const float*)d_in[5];
    const float* beta     = (const float*)d_in[6];
    const float* run_mean = (const float*)d_in[7];
    const float* run_var  = (const float*)d_in[8];
    float* out = (float*)d_out;

    // workspace: xhwc (26.2 MB) | wtb | woffb | scaleb
    unsigned short* xhwc  = (unsigned short*)d_ws;
    unsigned short* wtb   = xhwc + (size_t)NPIX * 64;          // 9*64*64 bf16
    unsigned short* woffb = wtb + 9 * Oo * Cc;                 // 9*32*64 bf16
    float* scaleb         = (float*)(woffb + 9 * 32 * Cc);     // 128 floats

    init_kernel<<<3200 + 144, 256, 0, stream>>>(
        x, xhwc, w_dcn, b_dcn, w_off, gamma, beta, run_mean, run_var,
        wtb, woffb, scaleb);

    dcn_kernel<<<NBLK, 256, 0, stream>>>(xhwc, wtb, woffb, b_off, scaleb, out);
}